// Round 9
// baseline (89.928 us; speedup 1.0000x reference)
//
#include <hip/hip_runtime.h>

#define K      32
#define TPB    256
#define NB     2048                 // blocks: 2048*256*4 = N; 8 blocks/CU
#define EPT    4                    // elements per thread (grid-stride)
#define NTOT   (32 * 64 * 1024)     // 2,097,152
#define STRIDE (TPB * NB)           // 524288

__device__ __forceinline__ float wave_reduce_sum(float v) {
#pragma unroll
  for (int m = 1; m < 64; m <<= 1) v += __shfl_xor(v, m, 64);
  return v;
}

__device__ __forceinline__ float to_sgpr(float v) {
  return __int_as_float(__builtin_amdgcn_readfirstlane(__float_as_int(v)));
}

// Allocator failure modes catalogued: caps->spill (R0/R2), full e-unroll->
// 256-reg balloon (R4), unroll2+arrays->scratch demotion (R7). R8's pair-split
// put 2 shuffles (~120cyc ds_bpermute) in the per-element chain. This round:
// NO t[] array at all — recompute exp2(Cf|d|) in a second k-loop once inv is
// known. Live set ~sAcc[32]+xs[4]+temps ≈ 70 VGPR -> 6-7 waves/SIMD, no
// shuffles in the chain, e-loop stays 'unroll 1' (only proven-safe setting).
__global__ __launch_bounds__(TPB)
void ssq_main(const float* __restrict__ x, const float* __restrict__ bins,
              float* __restrict__ out, float* __restrict__ partials) {
  const int tid  = threadIdx.x;
  const int base = blockIdx.x * TPB + tid;

  // wave-uniform -> SGPRs
  float binv[K];
#pragma unroll
  for (int k = 0; k < K; ++k) binv[k] = to_sgpr(bins[k]);
  float binsum = 0.f;
#pragma unroll
  for (int k = 0; k < K; ++k) binsum += binv[k];
  const float epsb = 1e-10f * binsum;     // eps * sum(bins) term of bit_code

  float xs[EPT];
#pragma unroll
  for (int e = 0; e < EPT; ++e) xs[e] = x[base + e * STRIDE];

  float sAcc[K];
#pragma unroll
  for (int k = 0; k < K; ++k) sAcc[k] = 0.f;
  float q = 0.f;

  const float Ch = -7.213475204444817f;   // 0.5 * ALPHA * log2(e)
  const float Cf = -14.426950408889634f;  // ALPHA * log2(e)

#pragma unroll 1
  for (int e = 0; e < EPT; ++e) {
    const float xv = xs[e];
    // ---- k-loop 1: denominators only, nothing stored per-k ----
    float s0 = 0.f, s1 = 0.f, h0 = 0.f, h1 = 0.f, b0 = 0.f, b1 = 0.f;
#pragma unroll
    for (int k = 0; k < K; k += 2) {
      float ha = __builtin_amdgcn_exp2f(Ch * fabsf(xv - binv[k + 0]));
      float hb = __builtin_amdgcn_exp2f(Ch * fabsf(xv - binv[k + 1]));
      float ta = ha * ha, tb = hb * hb;
      s0 += ta; s1 += tb;
      h0 += ha; h1 += hb;
      b0 = fmaf(ta, binv[k + 0], b0);
      b1 = fmaf(tb, binv[k + 1], b1);
    }
    const float s   = s0 + s1;
    const float inv = __builtin_amdgcn_rcpf(s);
    q = fmaf(h0 + h1, __builtin_amdgcn_rsqf(s), q);  // sum_k sqrt(a) = rsqrt(s)*sum h
    out[base + e * STRIDE] = fmaf(b0 + b1, inv, epsb);
    // ---- k-loop 2: recompute t = exp2(Cf|d|), accumulate normalized ----
#pragma unroll
    for (int k = 0; k < K; ++k) {
      float t = __builtin_amdgcn_exp2f(Cf * fabsf(xv - binv[k]));
      sAcc[k] = fmaf(t, inv, sAcc[k]);
    }
  }

  // block reduction: wave butterfly -> LDS -> one partial per counter
  __shared__ float red[4][K + 1];
  const int lane = tid & 63, wv = tid >> 6;
#pragma unroll
  for (int k = 0; k < K; ++k) {
    float v = wave_reduce_sum(sAcc[k]);
    if (lane == 0) red[wv][k] = v;
  }
  {
    float v = wave_reduce_sum(q);
    if (lane == 0) red[wv][K] = v;
  }
  __syncthreads();
  if (tid < K + 1) {
    float v = red[0][tid] + red[1][tid] + red[2][tid] + red[3][tid];
    partials[tid * NB + blockIdx.x] = v;   // written exactly once
  }
}

// 33 blocks: block c reduces partials[c*NB .. c*NB+NB) -> sums[c]
__global__ __launch_bounds__(TPB)
void ssq_reduce(const float* __restrict__ partials, float* __restrict__ sums) {
  const float* p = partials + blockIdx.x * NB;
  const int tid  = threadIdx.x;
  float s = 0.f;
#pragma unroll
  for (int j = 0; j < NB / TPB; ++j) s += p[tid + j * TPB];
  s = wave_reduce_sum(s);
  __shared__ float red[4];
  if ((tid & 63) == 0) red[tid >> 6] = s;
  __syncthreads();
  if (tid == 0) sums[blockIdx.x] = red[0] + red[1] + red[2] + red[3];
}

// one wave: entropy over 32 p_k + quant mean + tails
__global__ void ssq_final(const float* __restrict__ sums, float* __restrict__ out) {
  const int lane = threadIdx.x;
  float e = 0.f;
  if (lane < K) {
    float p = sums[lane] * (1.0f / (float)NTOT) + 1e-10f;  // eps folded in here
    e = -p * __logf(p);
  }
  e = wave_reduce_sum(e);
  if (lane == 0) {
    out[NTOT + 0] = e;                              // code entropy
    out[NTOT + 1] = 0.f;                            // TAU
    out[NTOT + 2] = sums[K] * (1.0f / (float)NTOT); // quant loss
    out[NTOT + 3] = 0.f;                            // TAU2
  }
}

extern "C" void kernel_launch(void* const* d_in, const int* in_sizes, int n_in,
                              void* d_out, int out_size, void* d_ws, size_t ws_size,
                              hipStream_t stream) {
  const float* x    = (const float*)d_in[0];
  const float* bins = (const float*)d_in[1];
  float* out        = (float*)d_out;
  float* partials   = (float*)d_ws;                 // (K+1)*NB floats = 264 KB
  float* sums       = partials + (K + 1) * NB;      // 33 floats

  ssq_main  <<<NB,    TPB, 0, stream>>>(x, bins, out, partials);
  ssq_reduce<<<K + 1, TPB, 0, stream>>>(partials, sums);
  ssq_final <<<1,     64,  0, stream>>>(sums, out);
}

// Round 10
// 87.463 us; speedup vs baseline: 1.0282x; 1.0282x over previous
//
#include <hip/hip_runtime.h>

#define K      32
#define KQ     8                    // bins per lane (K split across lane QUADS)
#define TPB    256
#define NB     4096                 // 4096 blocks * 64 quad-slots * 8 = N
#define EPT    8                    // elements per quad-slot
#define NTOT   (32 * 64 * 1024)     // 2,097,152
#define PSTRIDE (NB * (TPB / 4))    // 262144 quad-slots per sweep

__device__ __forceinline__ float wave_reduce_sum(float v) {
#pragma unroll
  for (int m = 1; m < 64; m <<= 1) v += __shfl_xor(v, m, 64);
  return v;
}

// reduce across the 16 lanes holding the same quarter: masks 4,8,16,32
__device__ __forceinline__ float quarter_reduce(float v) {
#pragma unroll
  for (int m = 4; m < 64; m <<= 1) v += __shfl_xor(v, m, 64);
  return v;
}

// Evolution of the split axis: full-K (R5, 1 elem in flight, chain 32) ->
// pair (R8, chain 16, 2 shuffles, ~5 waves/SIMD, best) -> QUAD (chain 8,
// 4 shuffles, arrays [8], live set ~52 regs -> 8 waves/SIMD). Issue cost is
// split-invariant (~7us); the split buys latency hiding. e-loop stays
// 'unroll 1' (only proven-safe setting; R4=balloon, R7=scratch demotion).
__global__ __launch_bounds__(TPB)
void ssq_main(const float* __restrict__ x, const float* __restrict__ bins,
              float* __restrict__ out, float* __restrict__ partials) {
  const int tid     = threadIdx.x;
  const int quarter = tid & 3;                    // which 8-bin quarter
  const int pslot   = blockIdx.x * (TPB / 4) + (tid >> 2);

  // this lane's 8 bins (parity-dependent -> VGPRs)
  float binv[KQ];
#pragma unroll
  for (int j = 0; j < KQ; ++j) binv[j] = bins[KQ * quarter + j];
  float bs = 0.f;
#pragma unroll
  for (int j = 0; j < KQ; ++j) bs += binv[j];
  bs += __shfl_xor(bs, 1, 64);
  bs += __shfl_xor(bs, 2, 64);                    // sum over all 32 bins
  const float epsb = 1e-10f * bs;                 // eps * sum(bins) term

  float xs[EPT];
#pragma unroll
  for (int e = 0; e < EPT; ++e) xs[e] = x[pslot + e * PSTRIDE];

  float sAcc[KQ];
#pragma unroll
  for (int j = 0; j < KQ; ++j) sAcc[j] = 0.f;
  float q = 0.f;

  const float Ch = -7.213475204444817f;           // 0.5 * ALPHA * log2(e)

#pragma unroll 1
  for (int e = 0; e < EPT; ++e) {
    const float xv = xs[e];
    float t[KQ];                                  // dies each iteration
    float s0 = 0.f, s1 = 0.f, h0 = 0.f, h1 = 0.f, b0 = 0.f, b1 = 0.f;
#pragma unroll
    for (int j = 0; j < KQ; j += 2) {
      float ha = __builtin_amdgcn_exp2f(Ch * fabsf(xv - binv[j + 0]));
      float hb = __builtin_amdgcn_exp2f(Ch * fabsf(xv - binv[j + 1]));
      float ta = ha * ha, tb = hb * hb;
      t[j + 0] = ta; t[j + 1] = tb;
      s0 += ta; s1 += tb;
      h0 += ha; h1 += hb;
      b0 = fmaf(ta, binv[j + 0], b0);
      b1 = fmaf(tb, binv[j + 1], b1);
    }
    float s_loc = s0 + s1, b_loc = b0 + b1;
    // combine the 4 quarters (xor butterfly leaves result on all lanes)
    float s2 = s_loc + __shfl_xor(s_loc, 1, 64);
    float b2 = b_loc + __shfl_xor(b_loc, 1, 64);
    const float s_full = s2 + __shfl_xor(s2, 2, 64);
    const float b_full = b2 + __shfl_xor(b2, 2, 64);
    const float inv = __builtin_amdgcn_rcpf(s_full);
    // local hsum * rsqrt(s): q summed over ALL lanes later = sum_k sqrt(a_k)
    q = fmaf(h0 + h1, __builtin_amdgcn_rsqf(s_full), q);
    if (quarter == 0) out[pslot + e * PSTRIDE] = fmaf(b_full, inv, epsb);
#pragma unroll
    for (int j = 0; j < KQ; ++j) sAcc[j] = fmaf(t[j], inv, sAcc[j]);
  }

  // block reduction. quarter_reduce leaves bin sums on all lanes; lanes 0-3
  // (lane==quarter there) write their 8 rows. q: full-wave reduce.
  __shared__ float red[4][K + 1];
  const int lane = tid & 63, wv = tid >> 6;
#pragma unroll
  for (int j = 0; j < KQ; ++j) {
    float v = quarter_reduce(sAcc[j]);
    if (lane < 4) red[wv][KQ * lane + j] = v;
  }
  {
    float v = wave_reduce_sum(q);
    if (lane == 0) red[wv][K] = v;
  }
  __syncthreads();
  if (tid < K + 1) {
    float v = red[0][tid] + red[1][tid] + red[2][tid] + red[3][tid];
    partials[tid * NB + blockIdx.x] = v;          // written exactly once
  }
}

// single block, 16 waves: wave w reduces rows {w, w+16, ...} of partials,
// then wave 0 does the entropy + writes the 4 tail floats. Replaces the
// former ssq_reduce+ssq_final pair (one dispatch fewer, no atomics).
__global__ __launch_bounds__(1024)
void ssq_tail(const float* __restrict__ partials, float* __restrict__ out) {
  const int tid = threadIdx.x, lane = tid & 63, wv = tid >> 6;
  __shared__ float sums[K + 1];
  for (int c = wv; c < K + 1; c += 16) {
    const float* p = partials + c * NB;
    float s = 0.f;
#pragma unroll
    for (int j = 0; j < NB / 64; ++j) s += p[lane + j * 64];
    s = wave_reduce_sum(s);
    if (lane == 0) sums[c] = s;
  }
  __syncthreads();
  if (wv == 0) {
    float e = 0.f;
    if (lane < K) {
      float p = sums[lane] * (1.0f / (float)NTOT) + 1e-10f;  // eps folded in
      e = -p * __logf(p);
    }
    e = wave_reduce_sum(e);
    if (lane == 0) {
      out[NTOT + 0] = e;                              // code entropy
      out[NTOT + 1] = 0.f;                            // TAU
      out[NTOT + 2] = sums[K] * (1.0f / (float)NTOT); // quant loss
      out[NTOT + 3] = 0.f;                            // TAU2
    }
  }
}

extern "C" void kernel_launch(void* const* d_in, const int* in_sizes, int n_in,
                              void* d_out, int out_size, void* d_ws, size_t ws_size,
                              hipStream_t stream) {
  const float* x    = (const float*)d_in[0];
  const float* bins = (const float*)d_in[1];
  float* out        = (float*)d_out;
  float* partials   = (float*)d_ws;                 // (K+1)*NB floats = 540 KB

  ssq_main<<<NB, TPB,  0, stream>>>(x, bins, out, partials);
  ssq_tail<<<1,  1024, 0, stream>>>(partials, out);
}

// Round 11
// 86.070 us; speedup vs baseline: 1.0448x; 1.0162x over previous
//
#include <hip/hip_runtime.h>

#define K      32
#define KQ     8                    // bins per lane (K split across lane QUADS)
#define TPB    256
#define NB     4096                 // 4096 blocks * 64 quad-slots * 8 = N
#define EPT    8                    // elements per quad-slot
#define NTOT   (32 * 64 * 1024)     // 2,097,152
#define PSTRIDE (NB * (TPB / 4))    // 262144 quad-slots per sweep

__device__ __forceinline__ float wave_reduce_sum(float v) {
#pragma unroll
  for (int m = 1; m < 64; m <<= 1) v += __shfl_xor(v, m, 64);
  return v;
}

// intra-quad xor via DPP quad_perm -- VALU pipe, ~4cyc, NO ds_bpermute.
// xor1: quad_perm[1,0,3,2] = 0xB1; xor2: quad_perm[2,3,0,1] = 0x4E.
__device__ __forceinline__ float dpp_xor1(float v) {
  return __int_as_float(__builtin_amdgcn_update_dpp(
      0, __float_as_int(v), 0xB1, 0xF, 0xF, true));
}
__device__ __forceinline__ float dpp_xor2(float v) {
  return __int_as_float(__builtin_amdgcn_update_dpp(
      0, __float_as_int(v), 0x4E, 0xF, 0xF, true));
}

// reduce across the 16 lanes holding the same quarter: masks 4,8,16,32
// (epilogue only -- off the critical path, plain shfl is fine)
__device__ __forceinline__ float quarter_reduce(float v) {
#pragma unroll
  for (int m = 4; m < 64; m <<= 1) v += __shfl_xor(v, m, 64);
  return v;
}

// R10 post-mortem: quad-split was neutral because the 2 dependent
// __shfl_xor (ds_bpermute, ~120cyc each, lgkmcnt wait) sat IN the
// per-element chain. This round: same quad structure, but the mask-1/2
// combines are intra-quad -> DPP quad_perm (~4cyc, VALU pipe). Chain/elem
// drops ~350 -> ~110 cyc = issue cost; arrays [8] keep live set ~55 regs
// -> 8 waves/SIMD. e-loop stays 'unroll 1' (R4=balloon, R7=demotion).
__global__ __launch_bounds__(TPB)
void ssq_main(const float* __restrict__ x, const float* __restrict__ bins,
              float* __restrict__ out, float* __restrict__ partials) {
  const int tid     = threadIdx.x;
  const int quarter = tid & 3;                    // which 8-bin quarter
  const int pslot   = blockIdx.x * (TPB / 4) + (tid >> 2);

  // this lane's 8 bins (parity-dependent -> VGPRs)
  float binv[KQ];
#pragma unroll
  for (int j = 0; j < KQ; ++j) binv[j] = bins[KQ * quarter + j];
  float bs = 0.f;
#pragma unroll
  for (int j = 0; j < KQ; ++j) bs += binv[j];
  bs += dpp_xor1(bs);
  bs += dpp_xor2(bs);                             // sum over all 32 bins
  const float epsb = 1e-10f * bs;                 // eps * sum(bins) term

  float xs[EPT];
#pragma unroll
  for (int e = 0; e < EPT; ++e) xs[e] = x[pslot + e * PSTRIDE];

  float sAcc[KQ];
#pragma unroll
  for (int j = 0; j < KQ; ++j) sAcc[j] = 0.f;
  float q = 0.f;

  const float Ch = -7.213475204444817f;           // 0.5 * ALPHA * log2(e)

#pragma unroll 1
  for (int e = 0; e < EPT; ++e) {
    const float xv = xs[e];
    float t[KQ];                                  // dies each iteration
    float s0 = 0.f, s1 = 0.f, h0 = 0.f, h1 = 0.f, b0 = 0.f, b1 = 0.f;
#pragma unroll
    for (int j = 0; j < KQ; j += 2) {
      float ha = __builtin_amdgcn_exp2f(Ch * fabsf(xv - binv[j + 0]));
      float hb = __builtin_amdgcn_exp2f(Ch * fabsf(xv - binv[j + 1]));
      float ta = ha * ha, tb = hb * hb;
      t[j + 0] = ta; t[j + 1] = tb;
      s0 += ta; s1 += tb;
      h0 += ha; h1 += hb;
      b0 = fmaf(ta, binv[j + 0], b0);
      b1 = fmaf(tb, binv[j + 1], b1);
    }
    float s_loc = s0 + s1, b_loc = b0 + b1;
    // combine the 4 quarters via DPP (stays on VALU pipe, no lgkmcnt)
    float s2 = s_loc + dpp_xor1(s_loc);
    float b2 = b_loc + dpp_xor1(b_loc);
    const float s_full = s2 + dpp_xor2(s2);
    const float b_full = b2 + dpp_xor2(b2);
    const float inv = __builtin_amdgcn_rcpf(s_full);
    // local hsum * rsqrt(s): q summed over ALL lanes later = sum_k sqrt(a_k)
    q = fmaf(h0 + h1, __builtin_amdgcn_rsqf(s_full), q);
    if (quarter == 0) out[pslot + e * PSTRIDE] = fmaf(b_full, inv, epsb);
#pragma unroll
    for (int j = 0; j < KQ; ++j) sAcc[j] = fmaf(t[j], inv, sAcc[j]);
  }

  // block reduction. quarter_reduce leaves bin sums on all lanes; lanes 0-3
  // (lane==quarter there) write their 8 rows. q: full-wave reduce.
  __shared__ float red[4][K + 1];
  const int lane = tid & 63, wv = tid >> 6;
#pragma unroll
  for (int j = 0; j < KQ; ++j) {
    float v = quarter_reduce(sAcc[j]);
    if (lane < 4) red[wv][KQ * lane + j] = v;
  }
  {
    float v = wave_reduce_sum(q);
    if (lane == 0) red[wv][K] = v;
  }
  __syncthreads();
  if (tid < K + 1) {
    float v = red[0][tid] + red[1][tid] + red[2][tid] + red[3][tid];
    partials[tid * NB + blockIdx.x] = v;          // written exactly once
  }
}

// 33 blocks: block c reduces partials[c*NB .. c*NB+NB) -> sums[c]
__global__ __launch_bounds__(TPB)
void ssq_reduce(const float* __restrict__ partials, float* __restrict__ sums) {
  const float* p = partials + blockIdx.x * NB;
  const int tid  = threadIdx.x;
  float s = 0.f;
#pragma unroll
  for (int j = 0; j < NB / TPB; ++j) s += p[tid + j * TPB];
  s = wave_reduce_sum(s);
  __shared__ float red[4];
  if ((tid & 63) == 0) red[tid >> 6] = s;
  __syncthreads();
  if (tid == 0) sums[blockIdx.x] = red[0] + red[1] + red[2] + red[3];
}

// one wave: entropy over 32 p_k + quant mean + tails
__global__ void ssq_final(const float* __restrict__ sums, float* __restrict__ out) {
  const int lane = threadIdx.x;
  float e = 0.f;
  if (lane < K) {
    float p = sums[lane] * (1.0f / (float)NTOT) + 1e-10f;  // eps folded in here
    e = -p * __logf(p);
  }
  e = wave_reduce_sum(e);
  if (lane == 0) {
    out[NTOT + 0] = e;                              // code entropy
    out[NTOT + 1] = 0.f;                            // TAU
    out[NTOT + 2] = sums[K] * (1.0f / (float)NTOT); // quant loss
    out[NTOT + 3] = 0.f;                            // TAU2
  }
}

extern "C" void kernel_launch(void* const* d_in, const int* in_sizes, int n_in,
                              void* d_out, int out_size, void* d_ws, size_t ws_size,
                              hipStream_t stream) {
  const float* x    = (const float*)d_in[0];
  const float* bins = (const float*)d_in[1];
  float* out        = (float*)d_out;
  float* partials   = (float*)d_ws;                 // (K+1)*NB floats = 540 KB
  float* sums       = partials + (K + 1) * NB;      // 33 floats

  ssq_main  <<<NB,    TPB, 0, stream>>>(x, bins, out, partials);
  ssq_reduce<<<K + 1, TPB, 0, stream>>>(partials, sums);
  ssq_final <<<1,     64,  0, stream>>>(sums, out);
}